// Round 3
// baseline (549.120 us; speedup 1.0000x reference)
//
#include <hip/hip_runtime.h>

// Swin shifted-window attention, fused. B=32, C=256, H=W=64, WIN=8, SHIFT=4,
// HEADS=8, HD=32, N=64 tokens/window.
// R3: 2 windows per 256-thread block (wave = 32 tokens x 48 cols in GEMM1 so
// each B ds_read_b128 feeds 2 MFMAs), direct global stores from PV accums
// (no o_s round trip), DPP-rotation softmax reductions (no ds_swizzle),
// XOR-swizzled vt. LDS 54016 B -> 3 blocks/CU.

typedef short short8  __attribute__((ext_vector_type(8)));   // 8 x bf16
typedef short short4v __attribute__((ext_vector_type(4)));   // 4 x bf16
typedef float f32x4   __attribute__((ext_vector_type(4)));

static __device__ __forceinline__ short f2bf(float f) {
    unsigned u = __float_as_uint(f);
    u = (u + 0x7fffu + ((u >> 16) & 1u)) >> 16;   // round-to-nearest-even
    return (short)u;
}

static __device__ __forceinline__ int region(int i) {
    // shift-mask region along one axis: [0,56)=0, [56,60)=1, [60,64)=2
    return (i < 56) ? 0 : ((i < 60) ? 1 : 2);
}

// 16-lane (DPP row) reductions on the VALU — off the LDS pipe.
#define DPP_ROR(x, n) __int_as_float(__builtin_amdgcn_update_dpp( \
    0, __float_as_int(x), 0x120 + (n), 0xF, 0xF, true))
static __device__ __forceinline__ float row16_max(float v) {
    v = fmaxf(v, DPP_ROR(v, 1));
    v = fmaxf(v, DPP_ROR(v, 2));
    v = fmaxf(v, DPP_ROR(v, 4));
    v = fmaxf(v, DPP_ROR(v, 8));
    return v;
}
static __device__ __forceinline__ float row16_sum(float v) {
    v += DPP_ROR(v, 1);
    v += DPP_ROR(v, 2);
    v += DPP_ROR(v, 4);
    v += DPP_ROR(v, 8);
    return v;
}

// Prologue: qkv_w fp32 [k=256][col=768] -> Wt bf16 [col=768][k=256] in d_ws.
__global__ void wt_transpose(const float* __restrict__ w, unsigned short* __restrict__ wt) {
    int col = blockIdx.x;      // 0..767
    int k   = threadIdx.x;     // 0..255
    float v = w[k * 768 + col];
    unsigned u = __float_as_uint(v);
    u = (u + 0x7fffu + ((u >> 16) & 1u)) >> 16;
    wt[col * 256 + k] = (unsigned short)u;
}

__global__ __launch_bounds__(256, 3) void swin_kernel(
    const float* __restrict__ x,            // (32,256,64,64)
    const unsigned short* __restrict__ wt,  // bf16 (768,256) transposed weights
    const float* __restrict__ qkv_b,        // (768,)
    const float* __restrict__ tbl,          // (225,8) rel-pos bias table
    float* __restrict__ out)                // (32,256,64,64)
{
    // LDS layout (bytes), total 54016 -> 3 blocks/CU (162048 <= 163840):
    //   w_s : 0     .. 25344   (48 x 264 bf16)   one 48-col weight half
    //   q_s : 25344 .. 35584   2 win x (64 x 40 bf16)
    //   k_s : 35584 .. 45824   2 win x (64 x 40 bf16)
    //   vt_s: 45824 .. 54016   2 win x (32 x 64 bf16, XOR-swizzled 16B units)
    //   p_s : alias w_s        2 win x (64 x 72 bf16) = 18432 B <= 25344
    __shared__ char smem[54016];
    unsigned short* w_s  = (unsigned short*)(smem);
    unsigned short* q_s  = (unsigned short*)(smem + 25344);
    unsigned short* k_s  = (unsigned short*)(smem + 35584);
    unsigned short* vt_s = (unsigned short*)(smem + 45824);
    unsigned short* p_s  = (unsigned short*)(smem);

    const int tid  = threadIdx.x;
    const int wave = tid >> 6;
    const int lane = tid & 63;
    const int ln   = lane & 15;
    const int quad = lane >> 4;

    // XCD swizzle: g%8 selects XCD. 4 blocks (8 ww) of a (b,wh) band stay on
    // one XCD, dispatched adjacently, so SHIFT-split cache lines merge in L2.
    const int g    = blockIdx.x;           // 0..1023
    const int xcd  = g & 7;
    const int jj   = g >> 3;               // 0..127
    const int wb   = jj & 3;               // ww-pair index
    const int band = xcd * 32 + (jj >> 2); // 0..255
    const int b    = band >> 3;            // image
    const int wh   = band & 7;             // window row
    const int ww0  = wb * 2;               // first window col of this block

    // wave -> (window, 32-token row block)
    const int win = wave >> 1;             // 0..1
    const int rb  = (wave & 1) * 32;       // token base within window
    const int wwA = ww0 + win;

    unsigned short* qw = q_s  + win * 2560;  // 64x40
    unsigned short* kw = k_s  + win * 2560;
    unsigned short* vw = vt_s + win * 2048;  // 32x64 swizzled
    unsigned short* pw = p_s  + win * 4608;  // 64x72

    // ---- A fragments: wave's 32 tokens x 256 channels, bf16, in registers.
    // afrag[mt][ks]: A[m=ln][k=quad*8+j], token = rb + mt*16 + ln.
    short8 afrag[2][8];
    #pragma unroll
    for (int mt = 0; mt < 2; ++mt) {
        int t  = rb + mt * 16 + ln;          // local token 0..63
        int ti = t >> 3, tj = t & 7;
        int si = (wh * 8 + ti + 4) & 63;     // roll(-SHIFT) source
        int sj = (wwA * 8 + tj + 4) & 63;
        const float* xb = x + ((size_t)b * 256) * 4096 + si * 64 + sj;
        #pragma unroll
        for (int ks = 0; ks < 8; ++ks)
            #pragma unroll
            for (int j = 0; j < 8; ++j)
                afrag[mt][ks][j] = f2bf(xb[(size_t)(ks * 32 + quad * 8 + j) * 4096]);
    }

    for (int h = 0; h < 8; ++h) {
        // ---- GEMM1 in two 48-col halves (cols: q0-31,k0-15 | k16-31,v0-31)
        #pragma unroll
        for (int half = 0; half < 2; ++half) {
            __syncthreads();   // prior w_s/p_s readers done

            // stage 48 cols into w_s[col][k], stride 264 shorts
            #pragma unroll
            for (int i = 0; i < 6; ++i) {
                int idx = i * 256 + tid;              // 0..1535
                int cl  = idx >> 5;                   // 0..47
                int ch  = idx & 31;
                int colL = half * 48 + cl;
                int col  = ((colL >> 5) << 8) + (h << 5) + (colL & 31);
                *(short8*)(w_s + cl * 264 + ch * 8) =
                    *(const short8*)(wt + col * 256 + ch * 8);
            }
            __syncthreads();

            // (32 tok x 256) @ (256 x 48): each B-read feeds 2 MFMAs
            f32x4 acc[2][3];
            #pragma unroll
            for (int mt = 0; mt < 2; ++mt)
                #pragma unroll
                for (int jt = 0; jt < 3; ++jt) acc[mt][jt] = (f32x4){0.f,0.f,0.f,0.f};
            #pragma unroll
            for (int ks = 0; ks < 8; ++ks) {
                #pragma unroll
                for (int jt = 0; jt < 3; ++jt) {
                    short8 bb = *(const short8*)(w_s + (jt * 16 + ln) * 264 + ks * 32 + quad * 8);
                    acc[0][jt] = __builtin_amdgcn_mfma_f32_16x16x32_bf16(afrag[0][ks], bb, acc[0][jt], 0, 0, 0);
                    acc[1][jt] = __builtin_amdgcn_mfma_f32_16x16x32_bf16(afrag[1][ks], bb, acc[1][jt], 0, 0, 0);
                }
            }
            // epilogue: +bias; q scaled; q/k row-major, v transposed+packed
            #pragma unroll
            for (int jt = 0; jt < 3; ++jt) {
                const int seg = (half == 0) ? (jt < 2 ? 0 : 1) : (jt == 0 ? 1 : 2);
                int cc = ((half * 48 + jt * 16) & 31) + ln;
                float bias = qkv_b[(seg << 8) + (h << 5) + cc];
                #pragma unroll
                for (int mt = 0; mt < 2; ++mt) {
                    int t0 = rb + mt * 16 + quad * 4;   // C/D row = quad*4+r
                    if (seg == 0) {
                        #pragma unroll
                        for (int r = 0; r < 4; ++r)
                            qw[(t0 + r) * 40 + cc] =
                                (unsigned short)f2bf((acc[mt][jt][r] + bias) * 0.17677669529663689f);
                    } else if (seg == 1) {
                        #pragma unroll
                        for (int r = 0; r < 4; ++r)
                            kw[(t0 + r) * 40 + cc] = (unsigned short)f2bf(acc[mt][jt][r] + bias);
                    } else {
                        short4v pk;
                        #pragma unroll
                        for (int r = 0; r < 4; ++r) pk[r] = f2bf(acc[mt][jt][r] + bias);
                        // vt[cc][t0..t0+3], XOR-swizzled 16B units
                        int u = ((t0 >> 3) ^ (cc & 7)) << 3;
                        *(short4v*)(vw + cc * 64 + u + (t0 & 7)) = pk;
                    }
                }
            }
        }
        __syncthreads();   // q/k/vt visible to all waves; w_s reads done

        // ---- per-wave attention over its 32 q-rows (rows rb..rb+31 of win)
        short8 bk[4];
        #pragma unroll
        for (int nt = 0; nt < 4; ++nt)
            bk[nt] = *(const short8*)(kw + (nt * 16 + ln) * 40 + quad * 8);

        #pragma unroll
        for (int mt = 0; mt < 2; ++mt) {
            int t0 = rb + mt * 16;
            short8 aq = *(const short8*)(qw + (t0 + ln) * 40 + quad * 8);
            f32x4 sacc[4];
            #pragma unroll
            for (int nt = 0; nt < 4; ++nt) {
                f32x4 z = (f32x4){0.f, 0.f, 0.f, 0.f};
                sacc[nt] = __builtin_amdgcn_mfma_f32_16x16x32_bf16(aq, bk[nt], z, 0, 0, 0);
            }
            // bias + shift-mask, analytic
            float sv[4][4];
            #pragma unroll
            for (int nt = 0; nt < 4; ++nt) {
                int tk  = nt * 16 + ln;
                int tik = tk >> 3, tjk = tk & 7;
                int cntk = region(wh * 8 + tik) * 3 + region(wwA * 8 + tjk);
                #pragma unroll
                for (int r = 0; r < 4; ++r) {
                    int tq  = t0 + quad * 4 + r;
                    int tiq = tq >> 3, tjq = tq & 7;
                    int idx = (tiq - tik + 7) * 15 + (tjq - tjk + 7);
                    int cntq = region(wh * 8 + tiq) * 3 + region(wwA * 8 + tjq);
                    float s = sacc[nt][r] + tbl[idx * 8 + h];
                    if (cntq != cntk) s -= 100.0f;
                    sv[nt][r] = s;
                }
            }
            // softmax: row's 64 values = 16 lanes (DPP row) x 4 nt-accums
            #pragma unroll
            for (int r = 0; r < 4; ++r) {
                float m = fmaxf(fmaxf(sv[0][r], sv[1][r]), fmaxf(sv[2][r], sv[3][r]));
                m = row16_max(m);
                float p0 = __expf(sv[0][r] - m);
                float p1 = __expf(sv[1][r] - m);
                float p2 = __expf(sv[2][r] - m);
                float p3 = __expf(sv[3][r] - m);
                float ssum = row16_sum(p0 + p1 + p2 + p3);
                float inv = 1.0f / ssum;
                int pr = (t0 + quad * 4 + r) * 72;
                pw[pr +      ln] = (unsigned short)f2bf(p0 * inv);
                pw[pr + 16 + ln] = (unsigned short)f2bf(p1 * inv);
                pw[pr + 32 + ln] = (unsigned short)f2bf(p2 * inv);
                pw[pr + 48 + ln] = (unsigned short)f2bf(p3 * inv);
            }

            // ---- PV: O = P @ V (16 rows x 32 hd, K=64). Same-wave LDS
            // in-order makes pw write->read safe without a barrier.
            f32x4 oacc[2];
            oacc[0] = (f32x4){0.f, 0.f, 0.f, 0.f};
            oacc[1] = (f32x4){0.f, 0.f, 0.f, 0.f};
            #pragma unroll
            for (int ks2 = 0; ks2 < 2; ++ks2) {
                short8 ap = *(const short8*)(pw + (t0 + ln) * 72 + ks2 * 32 + quad * 8);
                #pragma unroll
                for (int nt2 = 0; nt2 < 2; ++nt2) {
                    int cc = nt2 * 16 + ln;
                    int u  = ((ks2 * 4 + quad) ^ (cc & 7)) << 3;
                    short8 bv = *(const short8*)(vw + cc * 64 + u);
                    oacc[nt2] = __builtin_amdgcn_mfma_f32_16x16x32_bf16(ap, bv, oacc[nt2], 0, 0, 0);
                }
            }
            // ---- direct global stores: lane's 4 C-rows = 4 consecutive dj
            {
                int t0r = t0 + quad * 4;
                int ti  = t0r >> 3, tj0 = t0r & 7;      // tj0 in {0,4}
                int di  = (wh * 8 + ti + 4) & 63;
                int dj0 = (wwA * 8 + tj0 + 4) & 63;     // 4-aligned, no straddle
                #pragma unroll
                for (int nt2 = 0; nt2 < 2; ++nt2) {
                    int c = (h << 5) + nt2 * 16 + ln;
                    f32x4 ov;
                    #pragma unroll
                    for (int r = 0; r < 4; ++r) ov[r] = oacc[nt2][r];
                    *(f32x4*)(out + ((size_t)(b * 256 + c)) * 4096 + di * 64 + dj0) = ov;
                }
            }
        }
    }
}

extern "C" void kernel_launch(void* const* d_in, const int* in_sizes, int n_in,
                              void* d_out, int out_size, void* d_ws, size_t ws_size,
                              hipStream_t stream) {
    const float* x      = (const float*)d_in[0];
    const float* qkv_w  = (const float*)d_in[1];
    const float* qkv_b  = (const float*)d_in[2];
    const float* tbl    = (const float*)d_in[3];
    float* out          = (float*)d_out;
    unsigned short* Wt  = (unsigned short*)d_ws;   // needs 768*256*2 = 393216 B

    wt_transpose<<<dim3(768), dim3(256), 0, stream>>>(qkv_w, Wt);
    swin_kernel<<<dim3(1024), dim3(256), 0, stream>>>(x, Wt, qkv_b, tbl, out);
}